// Round 1
// baseline (2327.082 us; speedup 1.0000x reference)
//
#include <hip/hip_runtime.h>
#include <math.h>

namespace {
constexpr int kB = 4;
constexpr int kL = 4096;
constexpr int kC = 512;
constexpr int kH = 8;
constexpr int kLr = 1024;
constexpr int kCH = 2048;   // C * expansion(4)
constexpr int kKred = 3584; // 7 * C
constexpr float kEps = 1e-5f;
}

// ---------------- LayerNorm over last dim (C=512); one block (256 thr) per row ----------------
__global__ __launch_bounds__(256) void ln_kernel(const float* in, float* out,
                                                 const float* __restrict__ g,
                                                 const float* __restrict__ be) {
  const int row = blockIdx.x;
  const int tid = threadIdx.x;
  const float2 v = *(const float2*)(in + (size_t)row * kC + tid * 2);
  float s = v.x + v.y;
  float ss = v.x * v.x + v.y * v.y;
#pragma unroll
  for (int off = 32; off > 0; off >>= 1) {
    s += __shfl_down(s, off);
    ss += __shfl_down(ss, off);
  }
  __shared__ float wsum[4][2];
  __shared__ float mi[2];
  const int wave = tid >> 6, lane = tid & 63;
  if (lane == 0) { wsum[wave][0] = s; wsum[wave][1] = ss; }
  __syncthreads();
  if (tid == 0) {
    const float S = wsum[0][0] + wsum[1][0] + wsum[2][0] + wsum[3][0];
    const float SS = wsum[0][1] + wsum[1][1] + wsum[2][1] + wsum[3][1];
    const float mean = S * (1.0f / kC);
    const float var = SS * (1.0f / kC) - mean * mean;
    mi[0] = mean;
    mi[1] = rsqrtf(var + kEps);
  }
  __syncthreads();
  const float mean = mi[0], inv = mi[1];
  const float2 gg = *(const float2*)(g + tid * 2);
  const float2 bb = *(const float2*)(be + tid * 2);
  float2 o;
  o.x = (v.x - mean) * inv * gg.x + bb.x;
  o.y = (v.y - mean) * inv * gg.y + bb.y;
  *(float2*)(out + (size_t)row * kC + tid * 2) = o;
}

// ---------------- sum 4 split-K partials then LayerNorm ----------------
__global__ __launch_bounds__(256) void reduce4_ln_kernel(const float* __restrict__ P, float* __restrict__ out,
                                                         const float* __restrict__ g,
                                                         const float* __restrict__ be) {
  const int row = blockIdx.x;
  const int tid = threadIdx.x;
  const size_t stride = (size_t)kB * kLr * kC;
  float2 v = make_float2(0.f, 0.f);
#pragma unroll
  for (int z = 0; z < 4; ++z) {
    const float2 p = *(const float2*)(P + z * stride + (size_t)row * kC + tid * 2);
    v.x += p.x;
    v.y += p.y;
  }
  float s = v.x + v.y;
  float ss = v.x * v.x + v.y * v.y;
#pragma unroll
  for (int off = 32; off > 0; off >>= 1) {
    s += __shfl_down(s, off);
    ss += __shfl_down(ss, off);
  }
  __shared__ float wsum[4][2];
  __shared__ float mi[2];
  const int wave = tid >> 6, lane = tid & 63;
  if (lane == 0) { wsum[wave][0] = s; wsum[wave][1] = ss; }
  __syncthreads();
  if (tid == 0) {
    const float S = wsum[0][0] + wsum[1][0] + wsum[2][0] + wsum[3][0];
    const float SS = wsum[0][1] + wsum[1][1] + wsum[2][1] + wsum[3][1];
    const float mean = S * (1.0f / kC);
    const float var = SS * (1.0f / kC) - mean * mean;
    mi[0] = mean;
    mi[1] = rsqrtf(var + kEps);
  }
  __syncthreads();
  const float mean = mi[0], inv = mi[1];
  const float2 gg = *(const float2*)(g + tid * 2);
  const float2 bb = *(const float2*)(be + tid * 2);
  float2 o;
  o.x = (v.x - mean) * inv * gg.x + bb.x;
  o.y = (v.y - mean) * inv * gg.y + bb.y;
  *(float2*)(out + (size_t)row * kC + tid * 2) = o;
}

// ---------------- repack w_red (O,I,7) -> (O, t*512+i) ----------------
__global__ void repack_wred_kernel(const float* __restrict__ src, float* __restrict__ dst) {
  const int idx = blockIdx.x * 256 + threadIdx.x;
  if (idx >= kC * kKred) return;
  const int o = idx / kKred;
  const int rem = idx - o * kKred;
  const int t = rem >> 9;
  const int i = rem & (kC - 1);
  dst[idx] = src[(size_t)(o * kC + i) * 7 + t];
}

__device__ __forceinline__ float gelu_exact(float x) {
  return 0.5f * x * (1.0f + erff(x * 0.70710678118654752440f));
}

// ---------------- generic 128x128 fp32 GEMM: Out = A(MxK) * W(NxK)^T (+Res) ----------------
// MODE 0: plain A.  MODE 1: A gathered from h via reflect-pad stride-4 conv indexing (reducer).
// MODE 2: A = gelu(depthwise3(f1)) computed on the fly (MixFFN hidden).
template <int MODE>
__global__ __launch_bounds__(256) void gemm128_kernel(
    const float* __restrict__ A, const float* __restrict__ W,
    const float* __restrict__ Res, float* __restrict__ Out,
    int M, int N, int K, const float* __restrict__ aux) {
  __shared__ float As[8][128];
  __shared__ float Ws[8][128];
  const int tid = threadIdx.x;
  const int m0 = blockIdx.y * 128;
  const int n0 = blockIdx.x * 128;
  const int srow = tid >> 1;
  const int sk4 = (tid & 1) * 4;
  const int tx = tid & 15;
  const int ty = tid >> 4;
  const int r0 = ty * 8;
  float acc[8][8] = {};

  int kBeg = 0, kEnd = K;
  float* outp = Out;
  if (gridDim.z > 1) {
    const int kchunk = K / gridDim.z;
    kBeg = blockIdx.z * kchunk;
    kEnd = kBeg + kchunk;
    outp = Out + (size_t)blockIdx.z * M * N;
  }

  for (int k0 = kBeg; k0 < kEnd; k0 += 8) {
    __syncthreads();
    {
      const float4 wv = *(const float4*)(W + (size_t)(n0 + srow) * K + k0 + sk4);
      Ws[sk4 + 0][srow] = wv.x;
      Ws[sk4 + 1][srow] = wv.y;
      Ws[sk4 + 2][srow] = wv.z;
      Ws[sk4 + 3][srow] = wv.w;
    }
    float4 av;
    if (MODE == 0) {
      av = *(const float4*)(A + (size_t)(m0 + srow) * K + k0 + sk4);
    } else if (MODE == 1) {
      const int m = m0 + srow;
      const int b = m >> 10;          // / kLr
      const int lr = m & (kLr - 1);
      const int k = k0 + sk4;
      const int t = k >> 9;           // / kC
      const int i = k & (kC - 1);
      int pos = 4 * lr + t - 3;       // reflect pad 3
      pos = pos < 0 ? -pos : (pos >= kL ? 2 * kL - 2 - pos : pos);
      av = *(const float4*)(A + ((size_t)b * kL + pos) * kC + i);
    } else {
      const int m = m0 + srow;
      const int b = m >> 12;          // / kL
      const int l = m & (kL - 1);
      const int cc0 = k0 + sk4;       // hidden channel base (mult of 4)
      const int c = cc0 >> 2;         // group = input channel
      const int lm = (l == 0) ? 1 : l - 1;            // reflect pad 1
      const int lp = (l == kL - 1) ? kL - 2 : l + 1;
      const float* base = A + (size_t)b * kL * kC + c;
      const float x0 = base[(size_t)lm * kC];
      const float x1 = base[(size_t)l * kC];
      const float x2 = base[(size_t)lp * kC];
      const float4 w0 = *(const float4*)(aux + cc0 * 3);
      const float4 w1 = *(const float4*)(aux + cc0 * 3 + 4);
      const float4 w2 = *(const float4*)(aux + cc0 * 3 + 8);
      av.x = gelu_exact(w0.x * x0 + w0.y * x1 + w0.z * x2);
      av.y = gelu_exact(w0.w * x0 + w1.x * x1 + w1.y * x2);
      av.z = gelu_exact(w1.z * x0 + w1.w * x1 + w2.x * x2);
      av.w = gelu_exact(w2.y * x0 + w2.z * x1 + w2.w * x2);
    }
    As[sk4 + 0][srow] = av.x;
    As[sk4 + 1][srow] = av.y;
    As[sk4 + 2][srow] = av.z;
    As[sk4 + 3][srow] = av.w;
    __syncthreads();
#pragma unroll
    for (int kk = 0; kk < 8; ++kk) {
      float a[8], w[8];
      *(float4*)&a[0] = *(const float4*)&As[kk][r0];
      *(float4*)&a[4] = *(const float4*)&As[kk][r0 + 4];
      *(float4*)&w[0] = *(const float4*)&Ws[kk][tx * 4];
      *(float4*)&w[4] = *(const float4*)&Ws[kk][64 + tx * 4];
#pragma unroll
      for (int i = 0; i < 8; ++i)
#pragma unroll
        for (int j = 0; j < 8; ++j)
          acc[i][j] = fmaf(a[i], w[j], acc[i][j]);
    }
  }

  const bool doRes = (Res != nullptr) && (gridDim.z == 1);
#pragma unroll
  for (int i = 0; i < 8; ++i) {
    const size_t off0 = (size_t)(m0 + r0 + i) * N + n0 + tx * 4;
    const size_t off1 = off0 + 64;
    float4 o0, o1;
    o0.x = acc[i][0]; o0.y = acc[i][1]; o0.z = acc[i][2]; o0.w = acc[i][3];
    o1.x = acc[i][4]; o1.y = acc[i][5]; o1.z = acc[i][6]; o1.w = acc[i][7];
    if (doRes) {
      const float4 ra = *(const float4*)(Res + off0);
      const float4 rb = *(const float4*)(Res + off1);
      o0.x += ra.x; o0.y += ra.y; o0.z += ra.z; o0.w += ra.w;
      o1.x += rb.x; o1.y += rb.y; o1.z += rb.z; o1.w += rb.w;
    }
    *(float4*)(outp + off0) = o0;
    *(float4*)(outp + off1) = o1;
  }
}

// ---------------- flash attention fp32: per block = (64 q-rows, one head, one batch) ----------------
__global__ __launch_bounds__(256) void attn_kernel(
    const float* __restrict__ q, const float* __restrict__ k,
    const float* __restrict__ v, float* __restrict__ o) {
  __shared__ float Qs[64][64];
  __shared__ float Ks[64][68];
  __shared__ float VsT[64][68];  // transposed: VsT[d][kcol]
  __shared__ float Ss[64][68];
  __shared__ float mrow[64], lrow[64], srow[64];
  const int tid = threadIdx.x;
  const int qt = blockIdx.x;
  const int h = blockIdx.y;
  const int b = blockIdx.z;
  const int tx = tid & 15;
  const int ty = tid >> 4;
  const int r0 = ty * 4;

  const size_t qbase = ((size_t)b * kL + qt * 64) * kC + h * 64;
#pragma unroll
  for (int it = 0; it < 4; ++it) {
    const int f = tid + it * 256;
    const int row = f >> 4;
    const int d4 = (f & 15) * 4;
    float4 qv = *(const float4*)(q + qbase + (size_t)row * kC + d4);
    qv.x *= 0.125f; qv.y *= 0.125f; qv.z *= 0.125f; qv.w *= 0.125f;  // 1/sqrt(64)
    *(float4*)&Qs[row][d4] = qv;
  }
  if (tid < 64) { mrow[tid] = -1e30f; lrow[tid] = 0.0f; }
  float acc[4][4] = {};

  for (int kt = 0; kt < kLr / 64; ++kt) {
    __syncthreads();
    const size_t kvbase = ((size_t)b * kLr + kt * 64) * kC + h * 64;
#pragma unroll
    for (int it = 0; it < 4; ++it) {
      const int f = tid + it * 256;
      const int row = f >> 4;
      const int d4 = (f & 15) * 4;
      *(float4*)&Ks[row][d4] = *(const float4*)(k + kvbase + (size_t)row * kC + d4);
      const float4 vv = *(const float4*)(v + kvbase + (size_t)row * kC + d4);
      VsT[d4 + 0][row] = vv.x;
      VsT[d4 + 1][row] = vv.y;
      VsT[d4 + 2][row] = vv.z;
      VsT[d4 + 3][row] = vv.w;
    }
    __syncthreads();
    // ---- S = (Q*scale) K^T ; thread cols are {tx + 16j} (conflict-free) ----
    float s[4][4] = {};
#pragma unroll
    for (int dc = 0; dc < 64; dc += 4) {
      float qa[4][4], kf[4][4];
#pragma unroll
      for (int i = 0; i < 4; ++i) *(float4*)qa[i] = *(const float4*)&Qs[r0 + i][dc];
#pragma unroll
      for (int j = 0; j < 4; ++j) *(float4*)kf[j] = *(const float4*)&Ks[tx + 16 * j][dc];
#pragma unroll
      for (int i = 0; i < 4; ++i)
#pragma unroll
        for (int j = 0; j < 4; ++j)
          s[i][j] += qa[i][0] * kf[j][0] + qa[i][1] * kf[j][1] + qa[i][2] * kf[j][2] + qa[i][3] * kf[j][3];
    }
#pragma unroll
    for (int i = 0; i < 4; ++i)
#pragma unroll
      for (int j = 0; j < 4; ++j)
        Ss[r0 + i][tx + 16 * j] = s[i][j];
    __syncthreads();
    // ---- online softmax update (4 lanes per row) ----
    {
      const int row = tid >> 2;
      const int seg = tid & 3;
      float tmax = -1e30f;
#pragma unroll
      for (int j = 0; j < 16; ++j) tmax = fmaxf(tmax, Ss[row][seg * 16 + j]);
      tmax = fmaxf(tmax, __shfl_xor(tmax, 1));
      tmax = fmaxf(tmax, __shfl_xor(tmax, 2));
      const float mold = mrow[row];
      const float mnew = fmaxf(mold, tmax);
      float psum = 0.f;
#pragma unroll
      for (int j = 0; j < 16; ++j) {
        const float e = __expf(Ss[row][seg * 16 + j] - mnew);
        Ss[row][seg * 16 + j] = e;
        psum += e;
      }
      psum += __shfl_xor(psum, 1);
      psum += __shfl_xor(psum, 2);
      if (seg == 0) {
        const float sc = __expf(mold - mnew);
        lrow[row] = lrow[row] * sc + psum;
        mrow[row] = mnew;
        srow[row] = sc;
      }
    }
    __syncthreads();
    // ---- O = O*rescale + P V ; thread d-cols are {tx + 16j} ----
#pragma unroll
    for (int i = 0; i < 4; ++i) {
      const float sc = srow[r0 + i];
      acc[i][0] *= sc; acc[i][1] *= sc; acc[i][2] *= sc; acc[i][3] *= sc;
    }
#pragma unroll
    for (int cc = 0; cc < 64; cc += 4) {
      float p[4][4], vt[4][4];
#pragma unroll
      for (int i = 0; i < 4; ++i) *(float4*)p[i] = *(const float4*)&Ss[r0 + i][cc];
#pragma unroll
      for (int j = 0; j < 4; ++j) *(float4*)vt[j] = *(const float4*)&VsT[tx + 16 * j][cc];
#pragma unroll
      for (int i = 0; i < 4; ++i)
#pragma unroll
        for (int j = 0; j < 4; ++j)
          acc[i][j] += p[i][0] * vt[j][0] + p[i][1] * vt[j][1] + p[i][2] * vt[j][2] + p[i][3] * vt[j][3];
    }
  }
  const size_t obase = ((size_t)b * kL + qt * 64) * kC + h * 64;
#pragma unroll
  for (int i = 0; i < 4; ++i) {
    const float inv = 1.0f / lrow[r0 + i];
#pragma unroll
    for (int j = 0; j < 4; ++j)
      o[obase + (size_t)(r0 + i) * kC + tx + 16 * j] = acc[i][j] * inv;
  }
}

extern "C" void kernel_launch(void* const* d_in, const int* in_sizes, int n_in,
                              void* d_out, int out_size, void* d_ws, size_t ws_size,
                              hipStream_t stream) {
  const float* x      = (const float*)d_in[0];
  const float* w_q    = (const float*)d_in[1];
  const float* w_k    = (const float*)d_in[2];
  const float* w_v    = (const float*)d_in[3];
  const float* w_o    = (const float*)d_in[4];
  const float* w_red  = (const float*)d_in[5];
  const float* w_ffn1 = (const float*)d_in[6];
  const float* w_dw   = (const float*)d_in[7];
  const float* w_ffn2 = (const float*)d_in[8];
  const float* gam    = (const float*)d_in[9];
  const float* bet    = (const float*)d_in[10];
  float* out = (float*)d_out;
  float* ws = (float*)d_ws;

  const size_t nBLC = (size_t)kB * kL * kC;    // 8,388,608
  const size_t nBLrC = (size_t)kB * kLr * kC;  // 2,097,152
  float* wred_rp = ws;                          // C*Kred = 1,835,008 floats
  float* hbuf = wred_rp + (size_t)kC * kKred;   // h / attn-out / f          (BLC)
  float* redb = hbuf + nBLC;                    // reduced seq               (BLrC)
  float* qbuf = redb + nBLrC;                   // splitK scratch / q / f1   (BLC)
  float* kbuf = qbuf + nBLC;                    // k                         (BLrC)
  float* vbuf = kbuf + nBLrC;                   // v                         (BLrC)
  // total ws use: ~95 MB

  // 1) repack reducer conv weight
  repack_wred_kernel<<<(kC * kKred + 255) / 256, 256, 0, stream>>>(w_red, wred_rp);
  // 2) h = LN0(x)
  ln_kernel<<<kB * kL, 256, 0, stream>>>(x, hbuf, gam + 0 * kC, bet + 0 * kC);
  // 3) reducer conv as gather-GEMM, split-K=4 -> qbuf partials; then sum+LN1 -> redb
  gemm128_kernel<1><<<dim3(kC / 128, kB * kLr / 128, 4), 256, 0, stream>>>(
      hbuf, wred_rp, nullptr, qbuf, kB * kLr, kC, kKred, nullptr);
  reduce4_ln_kernel<<<kB * kLr, 256, 0, stream>>>(qbuf, redb, gam + 1 * kC, bet + 1 * kC);
  // 4) q = LN2(h w_q^T)
  gemm128_kernel<0><<<dim3(kC / 128, kB * kL / 128), 256, 0, stream>>>(
      hbuf, w_q, nullptr, qbuf, kB * kL, kC, kC, nullptr);
  ln_kernel<<<kB * kL, 256, 0, stream>>>(qbuf, qbuf, gam + 2 * kC, bet + 2 * kC);
  // 5) k = LN3(red w_k^T), v = LN4(red w_v^T)
  gemm128_kernel<0><<<dim3(kC / 128, kB * kLr / 128), 256, 0, stream>>>(
      redb, w_k, nullptr, kbuf, kB * kLr, kC, kC, nullptr);
  ln_kernel<<<kB * kLr, 256, 0, stream>>>(kbuf, kbuf, gam + 3 * kC, bet + 3 * kC);
  gemm128_kernel<0><<<dim3(kC / 128, kB * kLr / 128), 256, 0, stream>>>(
      redb, w_v, nullptr, vbuf, kB * kLr, kC, kC, nullptr);
  ln_kernel<<<kB * kLr, 256, 0, stream>>>(vbuf, vbuf, gam + 4 * kC, bet + 4 * kC);
  // 6) attention -> hbuf
  attn_kernel<<<dim3(kL / 64, kH, kB), 256, 0, stream>>>(qbuf, kbuf, vbuf, hbuf);
  // 7) h2 = attn_out w_o^T + x  -> d_out
  gemm128_kernel<0><<<dim3(kC / 128, kB * kL / 128), 256, 0, stream>>>(
      hbuf, w_o, x, out, kB * kL, kC, kC, nullptr);
  // 8) f = LN5(h2) -> hbuf
  ln_kernel<<<kB * kL, 256, 0, stream>>>(out, hbuf, gam + 5 * kC, bet + 5 * kC);
  // 9) f1 = f w_ffn1^T -> qbuf
  gemm128_kernel<0><<<dim3(kC / 128, kB * kL / 128), 256, 0, stream>>>(
      hbuf, w_ffn1, nullptr, qbuf, kB * kL, kC, kC, nullptr);
  // 10) out = gelu(dw3(f1)) w_ffn2^T + h2   (dwconv+gelu fused into A-loader)
  gemm128_kernel<2><<<dim3(kC / 128, kB * kL / 128), 256, 0, stream>>>(
      qbuf, w_ffn2, out, out, kB * kL, kC, kCH, w_dw);
}

// Round 2
// 510.032 us; speedup vs baseline: 4.5626x; 4.5626x over previous
//
#include <hip/hip_runtime.h>
#include <math.h>

typedef __attribute__((ext_vector_type(8))) short short8;
typedef __attribute__((ext_vector_type(4))) float f32x4;
typedef unsigned short u16;
typedef unsigned int u32;

namespace {
constexpr int kB = 4;
constexpr int kL = 4096;
constexpr int kC = 512;
constexpr int kH = 8;
constexpr int kLr = 1024;
constexpr int kCH = 2048;
constexpr int kKred = 3584;
constexpr float kEps = 1e-5f;
}

__device__ __forceinline__ float bf2f(u16 u) { return __uint_as_float(((u32)u) << 16); }
__device__ __forceinline__ u16 f2bf(float f) {
  u32 u = __float_as_uint(f);
  u32 r = (u + 0x7fffu + ((u >> 16) & 1u)) >> 16;
  return (u16)r;
}

__device__ __forceinline__ void gload_lds16(const void* g, void* l) {
  __builtin_amdgcn_global_load_lds(
      (const __attribute__((address_space(1))) unsigned int*)g,
      (__attribute__((address_space(3))) unsigned int*)l, 16, 0, 0);
}

// swizzled frag read: tile rows of 64 bf16 (128B), XOR (row&7) on 16B slot
__device__ __forceinline__ short8 ldsfrag(const u16* base, int row, int col16) {
  return *(const short8*)(base + (size_t)(((row << 3) + (col16 ^ (row & 7))) << 3));
}

// ---------------- weight fp32 -> bf16 ----------------
__global__ __launch_bounds__(256) void cvt_bf16_kernel(const float* __restrict__ in,
                                                       u16* __restrict__ out, int n) {
  const int i = (blockIdx.x * 256 + threadIdx.x) * 4;
  if (i >= n) return;
  const float4 v = *(const float4*)(in + i);
  u16 o[4] = {f2bf(v.x), f2bf(v.y), f2bf(v.z), f2bf(v.w)};
  *(unsigned long long*)(out + i) = *(unsigned long long*)o;
}

// ---------------- repack w_red (O,I,7) -> bf16 [O][t*512+i] ----------------
__global__ __launch_bounds__(256) void repack_wred_kernel(const float* __restrict__ src,
                                                          u16* __restrict__ dst) {
  const int idx = blockIdx.x * 256 + threadIdx.x;
  if (idx >= kC * kKred) return;
  const int o = idx / kKred;
  const int rem = idx - o * kKred;
  const int t = rem >> 9;
  const int i = rem & (kC - 1);
  dst[idx] = f2bf(src[(size_t)(o * kC + i) * 7 + t]);
}

// ---------------- LayerNorm fp32-in -> bf16-out. TMODE 0: row layout; 1: v-transpose ----------------
template <int TMODE>
__global__ __launch_bounds__(256) void ln_bf16_kernel(const float* __restrict__ in,
                                                      u16* __restrict__ out,
                                                      const float* __restrict__ g,
                                                      const float* __restrict__ be,
                                                      float oscale) {
  const int row = blockIdx.x;
  const int tid = threadIdx.x;
  const float2 v = *(const float2*)(in + (size_t)row * kC + tid * 2);
  float s = v.x + v.y;
  float ss = v.x * v.x + v.y * v.y;
#pragma unroll
  for (int off = 32; off > 0; off >>= 1) {
    s += __shfl_down(s, off);
    ss += __shfl_down(ss, off);
  }
  __shared__ float wsum[4][2];
  __shared__ float mi[2];
  const int wave = tid >> 6, lane = tid & 63;
  if (lane == 0) { wsum[wave][0] = s; wsum[wave][1] = ss; }
  __syncthreads();
  if (tid == 0) {
    const float S = wsum[0][0] + wsum[1][0] + wsum[2][0] + wsum[3][0];
    const float SS = wsum[0][1] + wsum[1][1] + wsum[2][1] + wsum[3][1];
    const float mean = S * (1.0f / kC);
    const float var = SS * (1.0f / kC) - mean * mean;
    mi[0] = mean;
    mi[1] = rsqrtf(var + kEps);
  }
  __syncthreads();
  const float mean = mi[0], inv = mi[1];
  const float2 gg = *(const float2*)(g + tid * 2);
  const float2 bb = *(const float2*)(be + tid * 2);
  const float ox = ((v.x - mean) * inv * gg.x + bb.x) * oscale;
  const float oy = ((v.y - mean) * inv * gg.y + bb.y) * oscale;
  if (TMODE == 0) {
    u16 o2[2] = {f2bf(ox), f2bf(oy)};
    *(u32*)(out + (size_t)row * kC + tid * 2) = *(u32*)o2;
  } else {
    // out[(b*8+h)*64+d][1024] <- row=(b*1024+lr), col=tid*2
    const int b = row >> 10, lr = row & (kLr - 1);
    const int c = tid * 2;
    const int hh = c >> 6, d = c & 63;
    const size_t base = ((size_t)((b << 3) + hh) * 64 + d) * kLr + lr;
    out[base] = f2bf(ox);
    out[base + kLr] = f2bf(oy);
  }
}

// ---------------- sum 4 split-K fp32 partials -> LN -> bf16 ----------------
__global__ __launch_bounds__(256) void reduce4_ln_kernel(const float* __restrict__ P,
                                                         u16* __restrict__ out,
                                                         const float* __restrict__ g,
                                                         const float* __restrict__ be) {
  const int row = blockIdx.x;
  const int tid = threadIdx.x;
  const size_t stride = (size_t)kB * kLr * kC;
  float2 v = make_float2(0.f, 0.f);
#pragma unroll
  for (int z = 0; z < 4; ++z) {
    const float2 p = *(const float2*)(P + z * stride + (size_t)row * kC + tid * 2);
    v.x += p.x;
    v.y += p.y;
  }
  float s = v.x + v.y;
  float ss = v.x * v.x + v.y * v.y;
#pragma unroll
  for (int off = 32; off > 0; off >>= 1) {
    s += __shfl_down(s, off);
    ss += __shfl_down(ss, off);
  }
  __shared__ float wsum[4][2];
  __shared__ float mi[2];
  const int wave = tid >> 6, lane = tid & 63;
  if (lane == 0) { wsum[wave][0] = s; wsum[wave][1] = ss; }
  __syncthreads();
  if (tid == 0) {
    const float S = wsum[0][0] + wsum[1][0] + wsum[2][0] + wsum[3][0];
    const float SS = wsum[0][1] + wsum[1][1] + wsum[2][1] + wsum[3][1];
    const float mean = S * (1.0f / kC);
    const float var = SS * (1.0f / kC) - mean * mean;
    mi[0] = mean;
    mi[1] = rsqrtf(var + kEps);
  }
  __syncthreads();
  const float mean = mi[0], inv = mi[1];
  const float2 gg = *(const float2*)(g + tid * 2);
  const float2 bb = *(const float2*)(be + tid * 2);
  u16 o2[2] = {f2bf((v.x - mean) * inv * gg.x + bb.x), f2bf((v.y - mean) * inv * gg.y + bb.y)};
  *(u32*)(out + (size_t)row * kC + tid * 2) = *(u32*)o2;
}

// ---------------- MFMA bf16 GEMM: Out = A(MxK) * W(NxK)^T (+Res fp32) ----------------
// MODE 0: plain bf16 A. MODE 1: reducer gather from h. MODE 2: A = gelu(dw3(f1)) on the fly.
template <int MODE, bool RES, bool OUTBF>
__global__ __launch_bounds__(256) void mgemm_kernel(
    const u16* __restrict__ A, const u16* __restrict__ W,
    const float* __restrict__ Res, float* __restrict__ OutF, u16* __restrict__ OutB,
    int M, int N, int K, const float* __restrict__ aux) {
  __shared__ __align__(16) u16 As[128 * 32];
  __shared__ __align__(16) u16 Bs[128 * 32];
  const int tid = threadIdx.x;
  const int lane = tid & 63, w = tid >> 6;
  const int m0 = blockIdx.y * 128, n0 = blockIdx.x * 128;
  const int wm = (w >> 1) * 64, wn = (w & 1) * 64;
  const f32x4 zero = {0.f, 0.f, 0.f, 0.f};
  f32x4 acc[4][4];
#pragma unroll
  for (int i = 0; i < 4; ++i)
#pragma unroll
    for (int j = 0; j < 4; ++j) acc[i][j] = zero;

  int kBeg = 0, kEnd = K;
  float* outp = OutF;
  if (gridDim.z > 1) {
    const int kc = K / gridDim.z;
    kBeg = blockIdx.z * kc;
    kEnd = kBeg + kc;
    outp = OutF + (size_t)blockIdx.z * M * N;
  }

  for (int k0 = kBeg; k0 < kEnd; k0 += 32) {
    __syncthreads();
    // ---- stage B (always global_load_lds) ----
#pragma unroll
    for (int c = 0; c < 2; ++c) {
      const int ci = w * 2 + c;
      const int idx = ci * 64 + lane;
      const int row = idx >> 2, c16 = idx & 3;
      gload_lds16(W + (size_t)(n0 + row) * K + k0 + c16 * 8, (char*)Bs + ci * 1024);
    }
    // ---- stage A ----
    if (MODE == 0) {
#pragma unroll
      for (int c = 0; c < 2; ++c) {
        const int ci = w * 2 + c;
        const int idx = ci * 64 + lane;
        const int row = idx >> 2, c16 = idx & 3;
        gload_lds16(A + (size_t)(m0 + row) * K + k0 + c16 * 8, (char*)As + ci * 1024);
      }
    } else if (MODE == 1) {
#pragma unroll
      for (int c = 0; c < 2; ++c) {
        const int ci = w * 2 + c;
        const int idx = ci * 64 + lane;
        const int row = idx >> 2, c16 = idx & 3;
        const int m = m0 + row;
        const int b = m >> 10, lr = m & (kLr - 1);
        const int k = k0 + c16 * 8;
        const int t = k >> 9, i = k & (kC - 1);
        int pos = 4 * lr + t - 3;
        pos = pos < 0 ? -pos : (pos >= kL ? 2 * kL - 2 - pos : pos);
        gload_lds16(A + ((size_t)(b << 12) + pos) * kC + i, (char*)As + ci * 1024);
      }
    } else {  // MODE 2: compute gelu(dw3(f1)) and ds_write
#pragma unroll
      for (int it = 0; it < 2; ++it) {
        const int idx = it * 256 + tid;
        const int row = idx >> 2, c16 = idx & 3;
        const int m = m0 + row;
        const int bb = m >> 12, l = m & (kL - 1);
        const int cc0 = k0 + c16 * 8;
        const int cg = cc0 >> 2;
        const int lm = (l == 0) ? 1 : l - 1;
        const int lp = (l == kL - 1) ? kL - 2 : l + 1;
        const u16* f1p = A + (size_t)(bb << 12) * kC;
        const u32 xm = *(const u32*)(f1p + (size_t)lm * kC + cg);
        const u32 x0 = *(const u32*)(f1p + (size_t)l * kC + cg);
        const u32 xp = *(const u32*)(f1p + (size_t)lp * kC + cg);
        const float xml = bf2f((u16)xm), xmh = bf2f((u16)(xm >> 16));
        const float x0l = bf2f((u16)x0), x0h = bf2f((u16)(x0 >> 16));
        const float xpl = bf2f((u16)xp), xph = bf2f((u16)(xp >> 16));
        float wv[24];
#pragma unroll
        for (int t = 0; t < 6; ++t)
          *(float4*)&wv[t * 4] = *(const float4*)(aux + (size_t)cc0 * 3 + t * 4);
        short8 pk;
#pragma unroll
        for (int j = 0; j < 8; ++j) {
          const float a_ = (j < 4) ? xml : xmh;
          const float b_ = (j < 4) ? x0l : x0h;
          const float c_ = (j < 4) ? xpl : xph;
          const float dw = wv[j * 3] * a_ + wv[j * 3 + 1] * b_ + wv[j * 3 + 2] * c_;
          const float gl = 0.5f * dw * (1.0f + erff(dw * 0.70710678118654752440f));
          pk[j] = (short)f2bf(gl);
        }
        *(short8*)((char*)As + row * 64 + c16 * 16) = pk;
      }
    }
    __syncthreads();
    // ---- compute: 16 mfma per wave ----
    short8 af[4], bfr[4];
#pragma unroll
    for (int mb = 0; mb < 4; ++mb)
      af[mb] = *(const short8*)(As + (size_t)(wm + mb * 16 + (lane & 15)) * 32 + ((lane >> 4) << 3));
#pragma unroll
    for (int nb = 0; nb < 4; ++nb)
      bfr[nb] = *(const short8*)(Bs + (size_t)(wn + nb * 16 + (lane & 15)) * 32 + ((lane >> 4) << 3));
#pragma unroll
    for (int mb = 0; mb < 4; ++mb)
#pragma unroll
      for (int nb = 0; nb < 4; ++nb)
        acc[mb][nb] = __builtin_amdgcn_mfma_f32_16x16x32_bf16(af[mb], bfr[nb], acc[mb][nb], 0, 0, 0);
  }

  // ---- epilogue ----
#pragma unroll
  for (int mb = 0; mb < 4; ++mb) {
#pragma unroll
    for (int r = 0; r < 4; ++r) {
      const int row = m0 + wm + mb * 16 + ((lane >> 4) << 2) + r;
#pragma unroll
      for (int nb = 0; nb < 4; ++nb) {
        const int col = n0 + wn + nb * 16 + (lane & 15);
        float vv = acc[mb][nb][r];
        if (RES) vv += Res[(size_t)row * N + col];
        if (OUTBF) OutB[(size_t)row * N + col] = f2bf(vv);
        else outp[(size_t)row * N + col] = vv;
      }
    }
  }
}

// ---------------- MFMA flash attention: block = 64 q-rows x (head, batch); 4 waves x 16 rows ----------------
__global__ __launch_bounds__(256) void attn_mfma_kernel(
    const u16* __restrict__ q, const u16* __restrict__ k,
    const u16* __restrict__ vt, u16* __restrict__ o) {
  __shared__ __align__(16) u16 Qs[64 * 64];
  __shared__ __align__(16) u16 Ks[64 * 64];
  __shared__ __align__(16) u16 Vs[64 * 64];
  __shared__ __align__(16) u16 Ps[4][16 * 64];
  const int tid = threadIdx.x;
  const int lane = tid & 63, w = tid >> 6;
  const int qt = blockIdx.x, h = blockIdx.y, b = blockIdx.z;
  const int q0 = qt << 6;

  // stage Q (swizzled source -> linear LDS)
#pragma unroll
  for (int c = 0; c < 2; ++c) {
    const int ci = w * 2 + c;
    const int a16 = ci * 64 + lane;
    const int r = a16 >> 3, c16 = a16 & 7;
    gload_lds16(q + (size_t)((b << 12) + q0 + r) * kC + (h << 6) + ((c16 ^ (r & 7)) << 3),
                (char*)Qs + ci * 1024);
  }

  const f32x4 zero = {0.f, 0.f, 0.f, 0.f};
  float m4[4] = {-1e30f, -1e30f, -1e30f, -1e30f};
  float l4[4] = {0.f, 0.f, 0.f, 0.f};
  f32x4 accO[4];
#pragma unroll
  for (int i = 0; i < 4; ++i) accO[i] = zero;

  for (int kt = 0; kt < kLr / 64; ++kt) {
    __syncthreads();  // prev compute done (and Q staged on first iter)
    const int kv0 = kt << 6;
#pragma unroll
    for (int c = 0; c < 2; ++c) {
      const int ci = w * 2 + c;
      const int a16 = ci * 64 + lane;
      const int r = a16 >> 3, c16 = a16 & 7;
      gload_lds16(k + (size_t)((b << 10) + kv0 + r) * kC + (h << 6) + ((c16 ^ (r & 7)) << 3),
                  (char*)Ks + ci * 1024);
      gload_lds16(vt + (size_t)(((b << 3) + h) * 64 + r) * kLr + kv0 + ((c16 ^ (r & 7)) << 3),
                  (char*)Vs + ci * 1024);
    }
    __syncthreads();  // staging complete
    // ---- S = Q K^T (q pre-scaled by 1/8 in its LN) ----
    f32x4 s[4];
#pragma unroll
    for (int nb = 0; nb < 4; ++nb) s[nb] = zero;
#pragma unroll
    for (int kst = 0; kst < 2; ++kst) {
      const short8 aq = ldsfrag(Qs, (w << 4) + (lane & 15), (kst << 2) + (lane >> 4));
#pragma unroll
      for (int nb = 0; nb < 4; ++nb) {
        const short8 bk = ldsfrag(Ks, (nb << 4) + (lane & 15), (kst << 2) + (lane >> 4));
        s[nb] = __builtin_amdgcn_mfma_f32_16x16x32_bf16(aq, bk, s[nb], 0, 0, 0);
      }
    }
    // ---- online softmax (rows = (lane>>4)*4+r, cols = (lane&15)+16nb) ----
    float sc[4];
#pragma unroll
    for (int r = 0; r < 4; ++r) {
      float pm = fmaxf(fmaxf(s[0][r], s[1][r]), fmaxf(s[2][r], s[3][r]));
      pm = fmaxf(pm, __shfl_xor(pm, 1));
      pm = fmaxf(pm, __shfl_xor(pm, 2));
      pm = fmaxf(pm, __shfl_xor(pm, 4));
      pm = fmaxf(pm, __shfl_xor(pm, 8));
      const float mnew = fmaxf(m4[r], pm);
      sc[r] = __expf(m4[r] - mnew);
      m4[r] = mnew;
    }
#pragma unroll
    for (int nb = 0; nb < 4; ++nb)
#pragma unroll
      for (int r = 0; r < 4; ++r) s[nb][r] = __expf(s[nb][r] - m4[r]);
#pragma unroll
    for (int r = 0; r < 4; ++r) {
      float ps = s[0][r] + s[1][r] + s[2][r] + s[3][r];
      ps += __shfl_xor(ps, 1);
      ps += __shfl_xor(ps, 2);
      ps += __shfl_xor(ps, 4);
      ps += __shfl_xor(ps, 8);
      l4[r] = l4[r] * sc[r] + ps;
    }
    // ---- write P to wave-private swizzled LDS tile ----
    u16* pw = &Ps[w][0];
#pragma unroll
    for (int nb = 0; nb < 4; ++nb)
#pragma unroll
      for (int r = 0; r < 4; ++r) {
        const int qrow = ((lane >> 4) << 2) + r;
        const int kv = (lane & 15) + (nb << 4);
        const int ba = (qrow << 7) + ((kv << 1) ^ ((qrow & 7) << 4));
        *(u16*)((char*)pw + ba) = f2bf(s[nb][r]);
      }
    // ---- rescale O, then O += P V ----
#pragma unroll
    for (int db = 0; db < 4; ++db)
#pragma unroll
      for (int r = 0; r < 4; ++r) accO[db][r] *= sc[r];
#pragma unroll
    for (int kvs = 0; kvs < 2; ++kvs) {
      const short8 ap = ldsfrag(&Ps[w][0], lane & 15, (kvs << 2) + (lane >> 4));
#pragma unroll
      for (int db = 0; db < 4; ++db) {
        const short8 bv = ldsfrag(Vs, (db << 4) + (lane & 15), (kvs << 2) + (lane >> 4));
        accO[db] = __builtin_amdgcn_mfma_f32_16x16x32_bf16(ap, bv, accO[db], 0, 0, 0);
      }
    }
  }
  // ---- final normalize + store bf16 ----
#pragma unroll
  for (int r = 0; r < 4; ++r) l4[r] = 1.0f / l4[r];
  const int qg = (b << 12) + q0 + (w << 4) + ((lane >> 4) << 2);
#pragma unroll
  for (int db = 0; db < 4; ++db)
#pragma unroll
    for (int r = 0; r < 4; ++r)
      o[(size_t)(qg + r) * kC + (h << 6) + (db << 4) + (lane & 15)] = f2bf(accO[db][r] * l4[r]);
}

extern "C" void kernel_launch(void* const* d_in, const int* in_sizes, int n_in,
                              void* d_out, int out_size, void* d_ws, size_t ws_size,
                              hipStream_t stream) {
  const float* x      = (const float*)d_in[0];
  const float* w_q    = (const float*)d_in[1];
  const float* w_k    = (const float*)d_in[2];
  const float* w_v    = (const float*)d_in[3];
  const float* w_o    = (const float*)d_in[4];
  const float* w_red  = (const float*)d_in[5];
  const float* w_ffn1 = (const float*)d_in[6];
  const float* w_dw   = (const float*)d_in[7];
  const float* w_ffn2 = (const float*)d_in[8];
  const float* gam    = (const float*)d_in[9];
  const float* bet    = (const float*)d_in[10];
  float* out = (float*)d_out;

  const size_t nBLC = (size_t)kB * kL * kC;    // 8,388,608
  const size_t nBLrC = (size_t)kB * kLr * kC;  // 2,097,152
  u16* us = (u16*)d_ws;
  u16* wqb   = us;                    // 262144
  u16* wkb   = wqb + 262144;
  u16* wvb   = wkb + 262144;
  u16* wob   = wvb + 262144;
  u16* wf1b  = wob + 262144;
  u16* wf2b  = wf1b + 262144;         // 1,048,576
  u16* wredb = wf2b + 1048576;        // 1,835,008
  u16* h_b   = wredb + 1835008;       // nBLC   (also: attn-out, f1)
  u16* q_b   = h_b + nBLC;            // nBLC   (also: f)
  u16* red_b = q_b + nBLC;            // nBLrC
  u16* k_b   = red_b + nBLrC;         // nBLrC
  u16* vt_b  = k_b + nBLrC;           // nBLrC
  float* S   = (float*)(vt_b + nBLrC);  // 8,388,608 fp32 scratch

  // weights -> bf16
  cvt_bf16_kernel<<<256, 256, 0, stream>>>(w_q, wqb, 262144);
  cvt_bf16_kernel<<<256, 256, 0, stream>>>(w_k, wkb, 262144);
  cvt_bf16_kernel<<<256, 256, 0, stream>>>(w_v, wvb, 262144);
  cvt_bf16_kernel<<<256, 256, 0, stream>>>(w_o, wob, 262144);
  cvt_bf16_kernel<<<256, 256, 0, stream>>>(w_ffn1, wf1b, 262144);
  cvt_bf16_kernel<<<1024, 256, 0, stream>>>(w_ffn2, wf2b, 1048576);
  repack_wred_kernel<<<7168, 256, 0, stream>>>(w_red, wredb);

  // h = LN0(x) -> bf16
  ln_bf16_kernel<0><<<kB * kL, 256, 0, stream>>>(x, h_b, gam, bet, 1.0f);
  // reducer: gather-GEMM splitK=4 -> S; sum+LN1 -> red_b
  mgemm_kernel<1, false, false><<<dim3(4, 32, 4), 256, 0, stream>>>(
      h_b, wredb, nullptr, S, nullptr, kB * kLr, kC, kKred, nullptr);
  reduce4_ln_kernel<<<kB * kLr, 256, 0, stream>>>(S, red_b, gam + kC, bet + kC);
  // q = LN2(h w_q^T) * 0.125
  mgemm_kernel<0, false, false><<<dim3(4, 128, 1), 256, 0, stream>>>(
      h_b, wqb, nullptr, S, nullptr, kB * kL, kC, kC, nullptr);
  ln_bf16_kernel<0><<<kB * kL, 256, 0, stream>>>(S, q_b, gam + 2 * kC, bet + 2 * kC, 0.125f);
  // k = LN3(red w_k^T)
  mgemm_kernel<0, false, false><<<dim3(4, 32, 1), 256, 0, stream>>>(
      red_b, wkb, nullptr, S, nullptr, kB * kLr, kC, kC, nullptr);
  ln_bf16_kernel<0><<<kB * kLr, 256, 0, stream>>>(S, k_b, gam + 3 * kC, bet + 3 * kC, 1.0f);
  // v = LN4(red w_v^T) -> transposed [b][h][d][Lr]
  mgemm_kernel<0, false, false><<<dim3(4, 32, 1), 256, 0, stream>>>(
      red_b, wvb, nullptr, S, nullptr, kB * kLr, kC, kC, nullptr);
  ln_bf16_kernel<1><<<kB * kLr, 256, 0, stream>>>(S, vt_b, gam + 4 * kC, bet + 4 * kC, 1.0f);
  // attention -> h_b (bf16)
  attn_mfma_kernel<<<dim3(kL / 64, kH, kB), 256, 0, stream>>>(q_b, k_b, vt_b, h_b);
  // h2 = attn w_o^T + x -> d_out (fp32)
  mgemm_kernel<0, true, false><<<dim3(4, 128, 1), 256, 0, stream>>>(
      h_b, wob, x, out, nullptr, kB * kL, kC, kC, nullptr);
  // f = LN5(h2) -> q_b
  ln_bf16_kernel<0><<<kB * kL, 256, 0, stream>>>(out, q_b, gam + 5 * kC, bet + 5 * kC, 1.0f);
  // f1 = f w_ffn1^T -> h_b (bf16)
  mgemm_kernel<0, false, true><<<dim3(4, 128, 1), 256, 0, stream>>>(
      q_b, wf1b, nullptr, nullptr, h_b, kB * kL, kC, kC, nullptr);
  // out = gelu(dw3(f1)) w_ffn2^T + h2 -> d_out
  mgemm_kernel<2, true, false><<<dim3(4, 128, 1), 256, 0, stream>>>(
      h_b, wf2b, out, out, nullptr, kB * kL, kC, kCH, w_dw);
}

// Round 3
// 377.325 us; speedup vs baseline: 6.1673x; 1.3517x over previous
//
#include <hip/hip_runtime.h>
#include <math.h>

typedef __attribute__((ext_vector_type(8))) short short8;
typedef __attribute__((ext_vector_type(4))) float f32x4;
typedef unsigned short u16;
typedef unsigned int u32;

namespace {
constexpr int kB = 4;
constexpr int kL = 4096;
constexpr int kC = 512;
constexpr int kH = 8;
constexpr int kLr = 1024;
constexpr int kCH = 2048;
constexpr int kKred = 3584;
constexpr float kEps = 1e-5f;
}

__device__ __forceinline__ float bf2f(u16 u) { return __uint_as_float(((u32)u) << 16); }
__device__ __forceinline__ u16 f2bf(float f) {
  u32 u = __float_as_uint(f);
  u32 r = (u + 0x7fffu + ((u >> 16) & 1u)) >> 16;
  return (u16)r;
}

__device__ __forceinline__ void gload_lds16(const void* g, void* l) {
  __builtin_amdgcn_global_load_lds(
      (const __attribute__((address_space(1))) unsigned int*)g,
      (__attribute__((address_space(3))) unsigned int*)l, 16, 0, 0);
}

// swizzled frag read: rows of 64 bf16 (128B), XOR (row&7) on 16B slot index
__device__ __forceinline__ short8 ldsfrag(const u16* base, int row, int col16) {
  return *(const short8*)(base + (size_t)(((row << 3) + (col16 ^ (row & 7))) << 3));
}

// ---------------- fused weight fp32 -> bf16 (wq|wk|wv|wo|wf1|wf2) ----------------
__global__ __launch_bounds__(256) void cvt_weights_kernel(
    const float* __restrict__ w_q, const float* __restrict__ w_k,
    const float* __restrict__ w_v, const float* __restrict__ w_o,
    const float* __restrict__ w_f1, const float* __restrict__ w_f2,
    u16* __restrict__ dst) {
  const int i = (blockIdx.x * 256 + threadIdx.x) * 4;  // total 2,359,296
  const int seg = i >> 18;                             // 262144 per segment
  const float* src;
  int off;
  if (seg < 5) {
    src = (seg == 0) ? w_q : (seg == 1) ? w_k : (seg == 2) ? w_v : (seg == 3) ? w_o : w_f1;
    off = i & 262143;
  } else {
    src = w_f2;
    off = i - 1310720;
  }
  const float4 v = *(const float4*)(src + off);
  u16 o[4] = {f2bf(v.x), f2bf(v.y), f2bf(v.z), f2bf(v.w)};
  *(unsigned long long*)(dst + i) = *(unsigned long long*)o;
}

// ---------------- repack w_red (O,I,7) -> bf16 [O][t*512+i] ----------------
__global__ __launch_bounds__(256) void repack_wred_kernel(const float* __restrict__ src,
                                                          u16* __restrict__ dst) {
  const int idx = blockIdx.x * 256 + threadIdx.x;
  if (idx >= kC * kKred) return;
  const int o = idx / kKred;
  const int rem = idx - o * kKred;
  const int t = rem >> 9;
  const int i = rem & (kC - 1);
  dst[idx] = f2bf(src[(size_t)(o * kC + i) * 7 + t]);
}

// ---------------- LayerNorm -> bf16. TMODE 0: row layout; 1: v-transpose. TIN: float or u16 ----------------
template <int TMODE, typename TIN>
__global__ __launch_bounds__(256) void ln_bf16_kernel(const TIN* __restrict__ in,
                                                      u16* __restrict__ out,
                                                      const float* __restrict__ g,
                                                      const float* __restrict__ be,
                                                      float oscale) {
  const int row = blockIdx.x;
  const int tid = threadIdx.x;
  float vx, vy;
  if constexpr (sizeof(TIN) == 4) {
    const float2 v = *(const float2*)((const float*)in + (size_t)row * kC + tid * 2);
    vx = v.x; vy = v.y;
  } else {
    const u32 v = *(const u32*)((const u16*)in + (size_t)row * kC + tid * 2);
    vx = bf2f((u16)v); vy = bf2f((u16)(v >> 16));
  }
  float s = vx + vy;
  float ss = vx * vx + vy * vy;
#pragma unroll
  for (int off = 32; off > 0; off >>= 1) {
    s += __shfl_down(s, off);
    ss += __shfl_down(ss, off);
  }
  __shared__ float wsum[4][2];
  __shared__ float mi[2];
  const int wave = tid >> 6, lane = tid & 63;
  if (lane == 0) { wsum[wave][0] = s; wsum[wave][1] = ss; }
  __syncthreads();
  if (tid == 0) {
    const float S = wsum[0][0] + wsum[1][0] + wsum[2][0] + wsum[3][0];
    const float SS = wsum[0][1] + wsum[1][1] + wsum[2][1] + wsum[3][1];
    const float mean = S * (1.0f / kC);
    const float var = SS * (1.0f / kC) - mean * mean;
    mi[0] = mean;
    mi[1] = rsqrtf(var + kEps);
  }
  __syncthreads();
  const float mean = mi[0], inv = mi[1];
  const float2 gg = *(const float2*)(g + tid * 2);
  const float2 bb = *(const float2*)(be + tid * 2);
  const float ox = ((vx - mean) * inv * gg.x + bb.x) * oscale;
  const float oy = ((vy - mean) * inv * gg.y + bb.y) * oscale;
  if (TMODE == 0) {
    u16 o2[2] = {f2bf(ox), f2bf(oy)};
    *(u32*)(out + (size_t)row * kC + tid * 2) = *(u32*)o2;
  } else {
    const int b = row >> 10, lr = row & (kLr - 1);
    const int c = tid * 2;
    const int hh = c >> 6, d = c & 63;
    const size_t base = ((size_t)((b << 3) + hh) * 64 + d) * kLr + lr;
    out[base] = f2bf(ox);
    out[base + kLr] = f2bf(oy);
  }
}

// ---------------- sum 4 split-K fp32 partials -> LN -> bf16 ----------------
__global__ __launch_bounds__(256) void reduce4_ln_kernel(const float* __restrict__ P,
                                                         u16* __restrict__ out,
                                                         const float* __restrict__ g,
                                                         const float* __restrict__ be) {
  const int row = blockIdx.x;
  const int tid = threadIdx.x;
  const size_t stride = (size_t)kB * kLr * kC;
  float2 v = make_float2(0.f, 0.f);
#pragma unroll
  for (int z = 0; z < 4; ++z) {
    const float2 p = *(const float2*)(P + z * stride + (size_t)row * kC + tid * 2);
    v.x += p.x;
    v.y += p.y;
  }
  float s = v.x + v.y;
  float ss = v.x * v.x + v.y * v.y;
#pragma unroll
  for (int off = 32; off > 0; off >>= 1) {
    s += __shfl_down(s, off);
    ss += __shfl_down(ss, off);
  }
  __shared__ float wsum[4][2];
  __shared__ float mi[2];
  const int wave = tid >> 6, lane = tid & 63;
  if (lane == 0) { wsum[wave][0] = s; wsum[wave][1] = ss; }
  __syncthreads();
  if (tid == 0) {
    const float S = wsum[0][0] + wsum[1][0] + wsum[2][0] + wsum[3][0];
    const float SS = wsum[0][1] + wsum[1][1] + wsum[2][1] + wsum[3][1];
    const float mean = S * (1.0f / kC);
    const float var = SS * (1.0f / kC) - mean * mean;
    mi[0] = mean;
    mi[1] = rsqrtf(var + kEps);
  }
  __syncthreads();
  const float mean = mi[0], inv = mi[1];
  const float2 gg = *(const float2*)(g + tid * 2);
  const float2 bb = *(const float2*)(be + tid * 2);
  u16 o2[2] = {f2bf((v.x - mean) * inv * gg.x + bb.x), f2bf((v.y - mean) * inv * gg.y + bb.y)};
  *(u32*)(out + (size_t)row * kC + tid * 2) = *(u32*)o2;
}

// ---------------- fdw = gelu(dwconv3(f1)); one block per sequence row ----------------
__global__ __launch_bounds__(256) void dwgelu_kernel(const u16* __restrict__ f1,
                                                     const float* __restrict__ wdw,
                                                     u16* __restrict__ fdw) {
  const int row = blockIdx.x;          // b*4096 + l
  const int l = row & (kL - 1);
  const int rb = row - l;              // b*4096
  const int cc0 = threadIdx.x * 8;     // hidden channel base
  const int cg = cc0 >> 2;             // input channel base (2 channels)
  const int lm = (l == 0) ? 1 : l - 1;
  const int lp = (l == kL - 1) ? kL - 2 : l + 1;
  const u32 xm = *(const u32*)(f1 + (size_t)(rb + lm) * kC + cg);
  const u32 x0 = *(const u32*)(f1 + (size_t)(rb + l) * kC + cg);
  const u32 xp = *(const u32*)(f1 + (size_t)(rb + lp) * kC + cg);
  const float xml = bf2f((u16)xm), xmh = bf2f((u16)(xm >> 16));
  const float x0l = bf2f((u16)x0), x0h = bf2f((u16)(x0 >> 16));
  const float xpl = bf2f((u16)xp), xph = bf2f((u16)(xp >> 16));
  float wv[24];
#pragma unroll
  for (int t = 0; t < 6; ++t)
    *(float4*)&wv[t * 4] = *(const float4*)(wdw + (size_t)cc0 * 3 + t * 4);
  short8 pk;
#pragma unroll
  for (int j = 0; j < 8; ++j) {
    const float a_ = (j < 4) ? xml : xmh;
    const float b_ = (j < 4) ? x0l : x0h;
    const float c_ = (j < 4) ? xpl : xph;
    const float dw = wv[j * 3] * a_ + wv[j * 3 + 1] * b_ + wv[j * 3 + 2] * c_;
    pk[j] = (short)f2bf(0.5f * dw * (1.0f + erff(dw * 0.70710678118654752440f)));
  }
  *(short8*)(fdw + (size_t)row * kCH + cc0) = pk;
}

// ---------------- MFMA bf16 GEMM, BK=64, XOR-swizzled LDS: Out = A(MxK) W(NxK)^T (+Res) ----------------
// MODE 0: plain bf16 A. MODE 1: reducer gather from h.
template <int MODE, bool RES, bool OUTBF>
__global__ __launch_bounds__(256) void mgemm_kernel(
    const u16* __restrict__ A, const u16* __restrict__ W,
    const float* __restrict__ Res, float* __restrict__ OutF, u16* __restrict__ OutB,
    int M, int N, int K) {
  __shared__ __align__(16) u16 As[128 * 64];
  __shared__ __align__(16) u16 Bs[128 * 64];
  const int tid = threadIdx.x;
  const int lane = tid & 63, w = tid >> 6;
  const int m0 = blockIdx.y * 128, n0 = blockIdx.x * 128;
  const int wm = (w >> 1) * 64, wn = (w & 1) * 64;
  const f32x4 zero = {0.f, 0.f, 0.f, 0.f};
  f32x4 acc[4][4];
#pragma unroll
  for (int i = 0; i < 4; ++i)
#pragma unroll
    for (int j = 0; j < 4; ++j) acc[i][j] = zero;

  int kBeg = 0, kEnd = K;
  float* outp = OutF;
  if (gridDim.z > 1) {
    const int kc = K / gridDim.z;
    kBeg = blockIdx.z * kc;
    kEnd = kBeg + kc;
    outp = OutF + (size_t)blockIdx.z * M * N;
  }

  for (int k0 = kBeg; k0 < kEnd; k0 += 64) {
    __syncthreads();
    // ---- stage B: 4 chunks/wave, swizzled source -> linear LDS ----
#pragma unroll
    for (int c = 0; c < 4; ++c) {
      const int ci = w * 4 + c;
      const int idx = ci * 64 + lane;
      const int row = idx >> 3, s = idx & 7;
      const int c16 = s ^ (row & 7);
      gload_lds16(W + (size_t)(n0 + row) * K + k0 + c16 * 8, (char*)Bs + ci * 1024);
    }
    // ---- stage A ----
    if (MODE == 0) {
#pragma unroll
      for (int c = 0; c < 4; ++c) {
        const int ci = w * 4 + c;
        const int idx = ci * 64 + lane;
        const int row = idx >> 3, s = idx & 7;
        const int c16 = s ^ (row & 7);
        gload_lds16(A + (size_t)(m0 + row) * K + k0 + c16 * 8, (char*)As + ci * 1024);
      }
    } else {  // reducer gather
#pragma unroll
      for (int c = 0; c < 4; ++c) {
        const int ci = w * 4 + c;
        const int idx = ci * 64 + lane;
        const int row = idx >> 3, s = idx & 7;
        const int c16 = s ^ (row & 7);
        const int m = m0 + row;
        const int b = m >> 10, lr = m & (kLr - 1);
        const int k = k0 + c16 * 8;
        const int t = k >> 9, i = k & (kC - 1);
        int pos = 4 * lr + t - 3;
        pos = pos < 0 ? -pos : (pos >= kL ? 2 * kL - 2 - pos : pos);
        gload_lds16(A + ((size_t)(b << 12) + pos) * kC + i, (char*)As + ci * 1024);
      }
    }
    __syncthreads();
    // ---- compute: 2 k-slices x 16 MFMA ----
#pragma unroll
    for (int kst = 0; kst < 2; ++kst) {
      short8 af[4], bfr[4];
      const int c16 = kst * 4 + (lane >> 4);
#pragma unroll
      for (int mb = 0; mb < 4; ++mb) af[mb] = ldsfrag(As, wm + mb * 16 + (lane & 15), c16);
#pragma unroll
      for (int nb = 0; nb < 4; ++nb) bfr[nb] = ldsfrag(Bs, wn + nb * 16 + (lane & 15), c16);
#pragma unroll
      for (int mb = 0; mb < 4; ++mb)
#pragma unroll
        for (int nb = 0; nb < 4; ++nb)
          acc[mb][nb] = __builtin_amdgcn_mfma_f32_16x16x32_bf16(af[mb], bfr[nb], acc[mb][nb], 0, 0, 0);
    }
  }

  // ---- epilogue ----
#pragma unroll
  for (int mb = 0; mb < 4; ++mb) {
#pragma unroll
    for (int r = 0; r < 4; ++r) {
      const int row = m0 + wm + mb * 16 + ((lane >> 4) << 2) + r;
#pragma unroll
      for (int nb = 0; nb < 4; ++nb) {
        const int col = n0 + wn + nb * 16 + (lane & 15);
        float vv = acc[mb][nb][r];
        if (RES) vv += Res[(size_t)row * N + col];
        if (OUTBF) OutB[(size_t)row * N + col] = f2bf(vv);
        else outp[(size_t)row * N + col] = vv;
      }
    }
  }
}

// ---------------- MFMA flash attention: block = 64 q-rows x (head, batch); 4 waves x 16 rows ----------------
__global__ __launch_bounds__(256) void attn_mfma_kernel(
    const u16* __restrict__ q, const u16* __restrict__ k,
    const u16* __restrict__ vt, u16* __restrict__ o) {
  __shared__ __align__(16) u16 Qs[64 * 64];
  __shared__ __align__(16) u16 Ks[64 * 64];
  __shared__ __align__(16) u16 Vs[64 * 64];
  __shared__ __align__(16) u16 Ps[4][16 * 64];
  const int tid = threadIdx.x;
  const int lane = tid & 63, w = tid >> 6;
  const int qt = blockIdx.x, h = blockIdx.y, b = blockIdx.z;
  const int q0 = qt << 6;

#pragma unroll
  for (int c = 0; c < 2; ++c) {
    const int ci = w * 2 + c;
    const int a16 = ci * 64 + lane;
    const int r = a16 >> 3, c16 = a16 & 7;
    gload_lds16(q + (size_t)((b << 12) + q0 + r) * kC + (h << 6) + ((c16 ^ (r & 7)) << 3),
                (char*)Qs + ci * 1024);
  }

  const f32x4 zero = {0.f, 0.f, 0.f, 0.f};
  float m4[4] = {-1e30f, -1e30f, -1e30f, -1e30f};
  float l4[4] = {0.f, 0.f, 0.f, 0.f};
  f32x4 accO[4];
#pragma unroll
  for (int i = 0; i < 4; ++i) accO[i] = zero;

  for (int kt = 0; kt < kLr / 64; ++kt) {
    __syncthreads();
    const int kv0 = kt << 6;
#pragma unroll
    for (int c = 0; c < 2; ++c) {
      const int ci = w * 2 + c;
      const int a16 = ci * 64 + lane;
      const int r = a16 >> 3, c16 = a16 & 7;
      gload_lds16(k + (size_t)((b << 10) + kv0 + r) * kC + (h << 6) + ((c16 ^ (r & 7)) << 3),
                  (char*)Ks + ci * 1024);
      gload_lds16(vt + (size_t)(((b << 3) + h) * 64 + r) * kLr + kv0 + ((c16 ^ (r & 7)) << 3),
                  (char*)Vs + ci * 1024);
    }
    __syncthreads();
    f32x4 s[4];
#pragma unroll
    for (int nb = 0; nb < 4; ++nb) s[nb] = zero;
#pragma unroll
    for (int kst = 0; kst < 2; ++kst) {
      const short8 aq = ldsfrag(Qs, (w << 4) + (lane & 15), (kst << 2) + (lane >> 4));
#pragma unroll
      for (int nb = 0; nb < 4; ++nb) {
        const short8 bk = ldsfrag(Ks, (nb << 4) + (lane & 15), (kst << 2) + (lane >> 4));
        s[nb] = __builtin_amdgcn_mfma_f32_16x16x32_bf16(aq, bk, s[nb], 0, 0, 0);
      }
    }
    float sc[4];
#pragma unroll
    for (int r = 0; r < 4; ++r) {
      float pm = fmaxf(fmaxf(s[0][r], s[1][r]), fmaxf(s[2][r], s[3][r]));
      pm = fmaxf(pm, __shfl_xor(pm, 1));
      pm = fmaxf(pm, __shfl_xor(pm, 2));
      pm = fmaxf(pm, __shfl_xor(pm, 4));
      pm = fmaxf(pm, __shfl_xor(pm, 8));
      const float mnew = fmaxf(m4[r], pm);
      sc[r] = __expf(m4[r] - mnew);
      m4[r] = mnew;
    }
#pragma unroll
    for (int nb = 0; nb < 4; ++nb)
#pragma unroll
      for (int r = 0; r < 4; ++r) s[nb][r] = __expf(s[nb][r] - m4[r]);
#pragma unroll
    for (int r = 0; r < 4; ++r) {
      float ps = s[0][r] + s[1][r] + s[2][r] + s[3][r];
      ps += __shfl_xor(ps, 1);
      ps += __shfl_xor(ps, 2);
      ps += __shfl_xor(ps, 4);
      ps += __shfl_xor(ps, 8);
      l4[r] = l4[r] * sc[r] + ps;
    }
    u16* pw = &Ps[w][0];
#pragma unroll
    for (int nb = 0; nb < 4; ++nb)
#pragma unroll
      for (int r = 0; r < 4; ++r) {
        const int qrow = ((lane >> 4) << 2) + r;
        const int kv = (lane & 15) + (nb << 4);
        const int ba = (qrow << 7) + ((kv << 1) ^ ((qrow & 7) << 4));
        *(u16*)((char*)pw + ba) = f2bf(s[nb][r]);
      }
#pragma unroll
    for (int db = 0; db < 4; ++db)
#pragma unroll
      for (int r = 0; r < 4; ++r) accO[db][r] *= sc[r];
#pragma unroll
    for (int kvs = 0; kvs < 2; ++kvs) {
      const short8 ap = ldsfrag(&Ps[w][0], lane & 15, (kvs << 2) + (lane >> 4));
#pragma unroll
      for (int db = 0; db < 4; ++db) {
        const short8 bv = ldsfrag(Vs, (db << 4) + (lane & 15), (kvs << 2) + (lane >> 4));
        accO[db] = __builtin_amdgcn_mfma_f32_16x16x32_bf16(ap, bv, accO[db], 0, 0, 0);
      }
    }
  }
#pragma unroll
  for (int r = 0; r < 4; ++r) l4[r] = 1.0f / l4[r];
  const int qg = (b << 12) + q0 + (w << 4) + ((lane >> 4) << 2);
#pragma unroll
  for (int db = 0; db < 4; ++db)
#pragma unroll
    for (int r = 0; r < 4; ++r)
      o[(size_t)(qg + r) * kC + (h << 6) + (db << 4) + (lane & 15)] = f2bf(accO[db][r] * l4[r]);
}

extern "C" void kernel_launch(void* const* d_in, const int* in_sizes, int n_in,
                              void* d_out, int out_size, void* d_ws, size_t ws_size,
                              hipStream_t stream) {
  const float* x      = (const float*)d_in[0];
  const float* w_q    = (const float*)d_in[1];
  const float* w_k    = (const float*)d_in[2];
  const float* w_v    = (const float*)d_in[3];
  const float* w_o    = (const float*)d_in[4];
  const float* w_red  = (const float*)d_in[5];
  const float* w_ffn1 = (const float*)d_in[6];
  const float* w_dw   = (const float*)d_in[7];
  const float* w_ffn2 = (const float*)d_in[8];
  const float* gam    = (const float*)d_in[9];
  const float* bet    = (const float*)d_in[10];
  float* out = (float*)d_out;

  const size_t nBLC = (size_t)kB * kL * kC;    // 8,388,608
  const size_t nBLrC = (size_t)kB * kLr * kC;  // 2,097,152
  u16* us = (u16*)d_ws;
  u16* wqb   = us;                    // 262144 x5 contiguous
  u16* wkb   = wqb + 262144;
  u16* wvb   = wkb + 262144;
  u16* wob   = wvb + 262144;
  u16* wf1b  = wob + 262144;
  u16* wf2b  = wf1b + 262144;         // 1,048,576
  u16* wredb = wf2b + 1048576;        // 1,835,008
  u16* h_b   = wredb + 1835008;       // nBLC (h / attn-out / f1)
  // pool (aliased): q_b|red_b|k_b|vt_b|S  and later  fdw (33,554,432 u16)
  u16* pool  = h_b + nBLC;
  u16* q_b   = pool;                  // nBLC (q / f)
  u16* red_b = q_b + nBLC;            // nBLrC
  u16* k_b   = red_b + nBLrC;         // nBLrC
  u16* vt_b  = k_b + nBLrC;           // nBLrC
  float* S   = (float*)(vt_b + nBLrC);  // nBLC fp32 scratch
  u16* Sb    = (u16*)S;                 // bf16 pre-LN scratch (same region)
  u16* fdw   = pool;                    // B*L*CH bf16, aliases q_b..S (all dead)

  // weights -> bf16 (one launch) + reducer repack
  cvt_weights_kernel<<<2304, 256, 0, stream>>>(w_q, w_k, w_v, w_o, w_ffn1, w_ffn2, wqb);
  repack_wred_kernel<<<7168, 256, 0, stream>>>(w_red, wredb);

  // h = LN0(x)
  ln_bf16_kernel<0, float><<<kB * kL, 256, 0, stream>>>(x, h_b, gam, bet, 1.0f);
  // reducer gather-GEMM splitK=4 -> S; sum+LN1 -> red_b
  mgemm_kernel<1, false, false><<<dim3(4, 32, 4), 256, 0, stream>>>(
      h_b, wredb, nullptr, S, nullptr, kB * kLr, kC, kKred);
  reduce4_ln_kernel<<<kB * kLr, 256, 0, stream>>>(S, red_b, gam + kC, bet + kC);
  // q = LN2(h w_q^T) * 0.125
  mgemm_kernel<0, false, true><<<dim3(4, 128, 1), 256, 0, stream>>>(
      h_b, wqb, nullptr, nullptr, Sb, kB * kL, kC, kC);
  ln_bf16_kernel<0, u16><<<kB * kL, 256, 0, stream>>>(Sb, q_b, gam + 2 * kC, bet + 2 * kC, 0.125f);
  // k = LN3(red w_k^T)
  mgemm_kernel<0, false, true><<<dim3(4, 32, 1), 256, 0, stream>>>(
      red_b, wkb, nullptr, nullptr, Sb, kB * kLr, kC, kC);
  ln_bf16_kernel<0, u16><<<kB * kLr, 256, 0, stream>>>(Sb, k_b, gam + 3 * kC, bet + 3 * kC, 1.0f);
  // v = LN4(red w_v^T) -> transposed [b][h][d][Lr]
  mgemm_kernel<0, false, true><<<dim3(4, 32, 1), 256, 0, stream>>>(
      red_b, wvb, nullptr, nullptr, Sb, kB * kLr, kC, kC);
  ln_bf16_kernel<1, u16><<<kB * kLr, 256, 0, stream>>>(Sb, vt_b, gam + 4 * kC, bet + 4 * kC, 1.0f);
  // attention -> h_b
  attn_mfma_kernel<<<dim3(kL / 64, kH, kB), 256, 0, stream>>>(q_b, k_b, vt_b, h_b);
  // h2 = attn w_o^T + x -> d_out (fp32)
  mgemm_kernel<0, true, false><<<dim3(4, 128, 1), 256, 0, stream>>>(
      h_b, wob, x, out, nullptr, kB * kL, kC, kC);
  // f = LN5(h2) -> q_b
  ln_bf16_kernel<0, float><<<kB * kL, 256, 0, stream>>>(out, q_b, gam + 5 * kC, bet + 5 * kC, 1.0f);
  // f1 = f w_ffn1^T -> h_b (bf16)
  mgemm_kernel<0, false, true><<<dim3(4, 128, 1), 256, 0, stream>>>(
      q_b, wf1b, nullptr, nullptr, h_b, kB * kL, kC, kC);
  // fdw = gelu(dw3(f1)) materialized once
  dwgelu_kernel<<<kB * kL, 256, 0, stream>>>(h_b, w_dw, fdw);
  // out = fdw w_ffn2^T + h2 -> d_out
  mgemm_kernel<0, true, false><<<dim3(4, 128, 1), 256, 0, stream>>>(
      fdw, wf2b, out, out, nullptr, kB * kL, kC, kCH);
}